// Round 1
// baseline (1597.760 us; speedup 1.0000x reference)
//
#include <hip/hip_runtime.h>
#include <stdint.h>

// ---------------------------------------------------------------------------
// HiSA transformer block on MI355X (gfx950), bf16-MFMA implementation.
// B=2, S=2048, D=1024, H=16, dk=64, F=4096.
// ---------------------------------------------------------------------------

typedef __attribute__((ext_vector_type(8))) short short8;     // 8 bf16 (4 VGPRs)
typedef __attribute__((ext_vector_type(4))) float f32x4;      // MFMA C/D frag
typedef __attribute__((ext_vector_type(4))) unsigned short u16x4;

__device__ __forceinline__ unsigned short f2bf(float f) {
    union { float f; unsigned u; } v; v.f = f;
    unsigned r = v.u + 0x7fffu + ((v.u >> 16) & 1u);   // round-to-nearest-even
    return (unsigned short)(r >> 16);
}

// async global->LDS, 16B per lane. LDS dest must be wave-uniform base + lane*16.
__device__ __forceinline__ void gload16(const void* gsrc, void* ldst) {
    __builtin_amdgcn_global_load_lds(
        (const __attribute__((address_space(1))) void*)gsrc,
        (__attribute__((address_space(3))) void*)ldst,
        16, 0, 0);
}

// ---------------------------------------------------------------------------
// f32 -> bf16 elementwise convert (vectorized)
// ---------------------------------------------------------------------------
__global__ __launch_bounds__(256) void f32_to_bf16_k(
    const float* __restrict__ in, unsigned short* __restrict__ out, int n4)
{
    int i = blockIdx.x * 256 + threadIdx.x;
    if (i < n4) {
        f32x4 v = *(const f32x4*)&in[(size_t)i * 4];
        u16x4 o = { f2bf(v[0]), f2bf(v[1]), f2bf(v[2]), f2bf(v[3]) };
        *(u16x4*)&out[(size_t)i * 4] = o;
    }
}

// ---------------------------------------------------------------------------
// W (K x N, f32) -> Wt (N x K, bf16) tiled transpose
// ---------------------------------------------------------------------------
__global__ __launch_bounds__(256) void transpose_k(
    const float* __restrict__ W, unsigned short* __restrict__ Wt, int K, int N)
{
    __shared__ float tile[32][33];
    const int n0 = blockIdx.x * 32, k0 = blockIdx.y * 32;
    const int tx = threadIdx.x & 31, ty = threadIdx.x >> 5;  // ty in [0,8)
#pragma unroll
    for (int i = 0; i < 32; i += 8)
        tile[ty + i][tx] = W[(size_t)(k0 + ty + i) * N + n0 + tx];
    __syncthreads();
#pragma unroll
    for (int i = 0; i < 32; i += 8)
        Wt[(size_t)(n0 + ty + i) * K + k0 + tx] = f2bf(tile[tx][ty + i]);
}

// ---------------------------------------------------------------------------
// concat bq|bk|bv -> bqkv (3072)
// ---------------------------------------------------------------------------
__global__ void concat3_k(const float* a, const float* b, const float* c, float* out)
{
    int i = blockIdx.x * 256 + threadIdx.x;
    if (i < 3072) out[i] = (i < 1024) ? a[i] : (i < 2048 ? b[i - 1024] : c[i - 2048]);
}

// ---------------------------------------------------------------------------
// mask dtype detection: 0 = int32 0/1, 1 = packed bytes, 2 = f32 0/1
// ---------------------------------------------------------------------------
__global__ __launch_bounds__(1024) void detect_mask_k(
    const unsigned int* __restrict__ m, int* __restrict__ flag)
{
    __shared__ int f1, f2;
    if (threadIdx.x == 0) { f1 = 0; f2 = 0; }
    __syncthreads();
    int l1 = 0, l2 = 0;
    for (int i = threadIdx.x; i < 262144; i += 1024) {
        unsigned v = m[i];
        l1 |= (v > 1u);
        l2 |= (v != 0u && v != 0x3f800000u);
    }
    if (l1) atomicOr(&f1, 1);
    if (l2) atomicOr(&f2, 1);
    __syncthreads();
    if (threadIdx.x == 0) {
        int mode = 0;
        if (f1) mode = f2 ? 1 : 2;
        *flag = mode;
    }
}

// ---------------------------------------------------------------------------
// GEMM: C(M,N) = A(M,K)bf16 @ Bt(N,K)bf16^T + bias
//   EPI 0: store bf16
//   EPI 1: relu, store bf16
//   EPI 2: + resid(M,N f32), store f32
// 128x128 tile, BK=64, 256 threads (4 waves, 2x2), 16x16x32 bf16 MFMA.
// ---------------------------------------------------------------------------
template<int EPI>
__global__ __launch_bounds__(256) void gemm_bt(
    const unsigned short* __restrict__ A, const unsigned short* __restrict__ Bt,
    const float* __restrict__ bias, const float* __restrict__ resid,
    void* __restrict__ Cout, int M, int N, int K)
{
    __shared__ unsigned short As[128 * 64];
    __shared__ unsigned short Bs[128 * 64];
    const int t = threadIdx.x;
    const int lane = t & 63, wid = t >> 6;
    const int l16 = lane & 15, g = lane >> 4;
    const int wr = wid >> 1, wc = wid & 1;
    const int bm = blockIdx.y * 128, bn = blockIdx.x * 128;

    f32x4 acc[4][4] = {};

    for (int k0 = 0; k0 < K; k0 += 64) {
        __syncthreads();   // all waves done reading previous tile
#pragma unroll
        for (int i = 0; i < 4; ++i) {
            int linear = i * 2048 + t * 8;
            int row = linear >> 6, col = linear & 63;
            gload16(&A[(size_t)(bm + row) * K + k0 + col], &As[linear]);
        }
#pragma unroll
        for (int i = 0; i < 4; ++i) {
            int linear = i * 2048 + t * 8;
            int row = linear >> 6, col = linear & 63;
            gload16(&Bt[(size_t)(bn + row) * K + k0 + col], &Bs[linear]);
        }
        __syncthreads();   // drains vmcnt -> LDS tile valid
#pragma unroll
        for (int kc = 0; kc < 2; ++kc) {
            short8 a[4], b[4];
#pragma unroll
            for (int m = 0; m < 4; ++m)
                a[m] = *(const short8*)&As[(wr * 64 + m * 16 + l16) * 64 + kc * 32 + g * 8];
#pragma unroll
            for (int n = 0; n < 4; ++n)
                b[n] = *(const short8*)&Bs[(wc * 64 + n * 16 + l16) * 64 + kc * 32 + g * 8];
#pragma unroll
            for (int m = 0; m < 4; ++m)
#pragma unroll
                for (int n = 0; n < 4; ++n)
                    acc[m][n] = __builtin_amdgcn_mfma_f32_16x16x32_bf16(a[m], b[n], acc[m][n], 0, 0, 0);
        }
    }

    // epilogue: C row = bm + wr*64 + m*16 + g*4 + r ; col = bn + wc*64 + n*16 + l16
#pragma unroll
    for (int m = 0; m < 4; ++m) {
        const int row0 = bm + wr * 64 + m * 16 + g * 4;
#pragma unroll
        for (int n = 0; n < 4; ++n) {
            const int col = bn + wc * 64 + n * 16 + l16;
            const float bb = bias[col];
#pragma unroll
            for (int r = 0; r < 4; ++r) {
                float v = acc[m][n][r] + bb;
                const size_t idx = (size_t)(row0 + r) * N + col;
                if (EPI == 2) {
                    ((float*)Cout)[idx] = v + resid[idx];
                } else {
                    if (EPI == 1) v = fmaxf(v, 0.f);
                    ((unsigned short*)Cout)[idx] = f2bf(v);
                }
            }
        }
    }
}

// ---------------------------------------------------------------------------
// Flash attention with dense mask.
// qkv: (4096 rows) x 3072 bf16, cols [0,1024)=Q, [1024,2048)=K, [2048,3072)=V
// grid: (S/64, B*H). block: 256 thr = 4 waves; wave w handles 16 q-rows.
// ctx out: (4096 x 1024) bf16, head-major cols.
// ---------------------------------------------------------------------------
__global__ __launch_bounds__(256) void attn_k(
    const unsigned short* __restrict__ qkv, const void* __restrict__ mask,
    const int* __restrict__ flag, unsigned short* __restrict__ ctx)
{
    __shared__ unsigned short Vt[64 * 72];        // [d][kk], padded stride 72
    __shared__ unsigned short Pl[4][16 * 72];     // per-wave P [q][kk]
    const int t = threadIdx.x, lane = t & 63, w = t >> 6;
    const int l16 = lane & 15, g = lane >> 4;
    const int bh = blockIdx.y;
    const int b = bh >> 4, h = bh & 15;
    const int q0 = blockIdx.x * 64;
    const int mode = *flag;

    // Q fragments (A-operand): lane holds Q[q0+w*16+l16][g*8+j (+32c)]
    const size_t rowQ = (size_t)(b * 2048 + q0 + w * 16 + l16) * 3072 + h * 64;
    short8 qf0 = *(const short8*)&qkv[rowQ + g * 8];
    short8 qf1 = *(const short8*)&qkv[rowQ + 32 + g * 8];

    f32x4 acc[4] = {};
    float mrow[4], lrow[4];
#pragma unroll
    for (int j = 0; j < 4; ++j) { mrow[j] = -INFINITY; lrow[j] = 0.f; }

    for (int kt = 0; kt < 32; ++kt) {
        __syncthreads();  // previous PV reads of Vt done
        // stage V tile transposed: Vt[d][kk] = V[kt*64+kk][d]
#pragma unroll
        for (int i = 0; i < 2; ++i) {
            int linear = i * 2048 + t * 8;
            int kk = linear >> 6, d0 = linear & 63;
            short8 vv = *(const short8*)&qkv[(size_t)(b * 2048 + kt * 64 + kk) * 3072 + 2048 + h * 64 + d0];
#pragma unroll
            for (int e = 0; e < 8; ++e)
                Vt[(d0 + e) * 72 + kk] = (unsigned short)vv[e];
        }
        __syncthreads();

        // S = Q K^T : 4 col-frags x 2 k-chunks
        f32x4 s[4] = {};
#pragma unroll
        for (int n = 0; n < 4; ++n) {
            const size_t rowK = (size_t)(b * 2048 + kt * 64 + n * 16 + l16) * 3072 + 1024 + h * 64;
            short8 kf0 = *(const short8*)&qkv[rowK + g * 8];
            short8 kf1 = *(const short8*)&qkv[rowK + 32 + g * 8];
            s[n] = __builtin_amdgcn_mfma_f32_16x16x32_bf16(qf0, kf0, s[n], 0, 0, 0);
            s[n] = __builtin_amdgcn_mfma_f32_16x16x32_bf16(qf1, kf1, s[n], 0, 0, 0);
        }

        // scale + mask. element: q = q0+w*16+g*4+j, kk = kt*64+n*16+l16
#pragma unroll
        for (int n = 0; n < 4; ++n) {
#pragma unroll
            for (int j = 0; j < 4; ++j) {
                const size_t midx =
                    (size_t)((size_t)bh * 2048 + q0 + w * 16 + g * 4 + j) * 2048 + kt * 64 + n * 16 + l16;
                bool keep;
                if (mode == 0)      keep = ((const int*)mask)[midx] != 0;
                else if (mode == 1) keep = ((const unsigned char*)mask)[midx] != 0;
                else                keep = ((const float*)mask)[midx] != 0.f;
                s[n][j] = keep ? s[n][j] * 0.125f : -1e30f;
            }
        }

        // online softmax per q-row (row = reg j within 16-lane group)
#pragma unroll
        for (int j = 0; j < 4; ++j) {
            float mx = fmaxf(fmaxf(s[0][j], s[1][j]), fmaxf(s[2][j], s[3][j]));
#pragma unroll
            for (int d = 1; d < 16; d <<= 1) mx = fmaxf(mx, __shfl_xor(mx, d));
            const float mn = fmaxf(mrow[j], mx);
            float p0 = __expf(s[0][j] - mn), p1 = __expf(s[1][j] - mn);
            float p2 = __expf(s[2][j] - mn), p3 = __expf(s[3][j] - mn);
            s[0][j] = p0; s[1][j] = p1; s[2][j] = p2; s[3][j] = p3;
            float sm = p0 + p1 + p2 + p3;
#pragma unroll
            for (int d = 1; d < 16; d <<= 1) sm += __shfl_xor(sm, d);
            const float scale = __expf(mrow[j] - mn);  // exp(-inf)=0 first tile
            lrow[j] = lrow[j] * scale + sm;
            mrow[j] = mn;
#pragma unroll
            for (int n = 0; n < 4; ++n) acc[n][j] *= scale;
        }

        // P (f32, C-layout) -> bf16 -> per-wave LDS [q][kk]
#pragma unroll
        for (int n = 0; n < 4; ++n)
#pragma unroll
            for (int j = 0; j < 4; ++j)
                Pl[w][(g * 4 + j) * 72 + n * 16 + l16] = f2bf(s[n][j]);
        // (per-wave region: in-wave LDS ordering suffices, no barrier)

        // O += P V : A = P from Pl, B = V from Vt
#pragma unroll
        for (int c = 0; c < 2; ++c) {
            short8 pf = *(const short8*)&Pl[w][l16 * 72 + c * 32 + g * 8];
#pragma unroll
            for (int n = 0; n < 4; ++n) {
                short8 vf = *(const short8*)&Vt[(n * 16 + l16) * 72 + c * 32 + g * 8];
                acc[n] = __builtin_amdgcn_mfma_f32_16x16x32_bf16(pf, vf, acc[n], 0, 0, 0);
            }
        }
    }

    // epilogue: ctx[b*2048+q][h*64 + n*16 + l16] = acc/l
#pragma unroll
    for (int n = 0; n < 4; ++n)
#pragma unroll
        for (int j = 0; j < 4; ++j) {
            const int q = q0 + w * 16 + g * 4 + j;
            ctx[(size_t)(b * 2048 + q) * 1024 + h * 64 + n * 16 + l16] = f2bf(acc[n][j] / lrow[j]);
        }
}

// ---------------------------------------------------------------------------
// row LayerNorm over 1024. WB=1: also write bf16 copy.
// ---------------------------------------------------------------------------
template<int WB>
__global__ __launch_bounds__(256) void ln_k(
    const float* __restrict__ in, const float* __restrict__ gw, const float* __restrict__ bw,
    float* __restrict__ outF, unsigned short* __restrict__ outB)
{
    __shared__ float red[2][4];
    const int row = blockIdx.x, t = threadIdx.x;
    const f32x4 v = *(const f32x4*)&in[(size_t)row * 1024 + t * 4];
    float s = v[0] + v[1] + v[2] + v[3];
    float ss = v[0] * v[0] + v[1] * v[1] + v[2] * v[2] + v[3] * v[3];
#pragma unroll
    for (int d = 1; d < 64; d <<= 1) { s += __shfl_xor(s, d); ss += __shfl_xor(ss, d); }
    if ((t & 63) == 0) { red[0][t >> 6] = s; red[1][t >> 6] = ss; }
    __syncthreads();
    s = red[0][0] + red[0][1] + red[0][2] + red[0][3];
    ss = red[1][0] + red[1][1] + red[1][2] + red[1][3];
    const float mu = s * (1.f / 1024.f);
    const float var = ss * (1.f / 1024.f) - mu * mu;
    const float rs = rsqrtf(var + 1e-5f);
    f32x4 y;
#pragma unroll
    for (int e = 0; e < 4; ++e)
        y[e] = (v[e] - mu) * rs * gw[t * 4 + e] + bw[t * 4 + e];
    *(f32x4*)&outF[(size_t)row * 1024 + t * 4] = y;
    if (WB) {
        u16x4 o = { f2bf(y[0]), f2bf(y[1]), f2bf(y[2]), f2bf(y[3]) };
        *(u16x4*)&outB[(size_t)row * 1024 + t * 4] = o;
    }
}

// ---------------------------------------------------------------------------
extern "C" void kernel_launch(void* const* d_in, const int* in_sizes, int n_in,
                              void* d_out, int out_size, void* d_ws, size_t ws_size,
                              hipStream_t stream)
{
    (void)in_sizes; (void)n_in; (void)out_size; (void)ws_size;
    const float* x   = (const float*)d_in[0];
    const void*  mask = d_in[1];
    const float* Wq  = (const float*)d_in[2];
    const float* bq  = (const float*)d_in[3];
    const float* Wk  = (const float*)d_in[4];
    const float* bk  = (const float*)d_in[5];
    const float* Wv  = (const float*)d_in[6];
    const float* bv  = (const float*)d_in[7];
    const float* Wo  = (const float*)d_in[8];
    const float* bo  = (const float*)d_in[9];
    const float* g1  = (const float*)d_in[10];
    const float* be1 = (const float*)d_in[11];
    const float* g2  = (const float*)d_in[12];
    const float* be2 = (const float*)d_in[13];
    const float* W1  = (const float*)d_in[14];
    const float* b1  = (const float*)d_in[15];
    const float* W2  = (const float*)d_in[16];
    const float* b2  = (const float*)d_in[17];

    const int M = 4096;   // B*S

    char* wsb = (char*)d_ws;
    size_t off = 0;
    auto alloc = [&](size_t bytes) -> char* {
        char* p = wsb + off;
        off += (bytes + 255) & ~(size_t)255;
        return p;
    };
    int*            flag   = (int*)           alloc(256);
    unsigned short* xb     = (unsigned short*)alloc((size_t)M * 1024 * 2);
    unsigned short* wqkvT  = (unsigned short*)alloc((size_t)3072 * 1024 * 2);
    unsigned short* woT    = (unsigned short*)alloc((size_t)1024 * 1024 * 2);
    unsigned short* w1T    = (unsigned short*)alloc((size_t)4096 * 1024 * 2);
    unsigned short* w2T    = (unsigned short*)alloc((size_t)1024 * 4096 * 2);
    float*          bqkv   = (float*)         alloc(3072 * 4);
    unsigned short* qkv    = (unsigned short*)alloc((size_t)M * 3072 * 2);
    unsigned short* ctxb   = (unsigned short*)alloc((size_t)M * 1024 * 2);
    float*          r1f    = (float*)         alloc((size_t)M * 1024 * 4);
    float*          x1f    = (float*)         alloc((size_t)M * 1024 * 4);
    unsigned short* x1b    = (unsigned short*)alloc((size_t)M * 1024 * 2);
    unsigned short* hb     = (unsigned short*)alloc((size_t)M * 4096 * 2);
    // total ~143 MB

    detect_mask_k<<<1, 1024, 0, stream>>>((const unsigned int*)mask, flag);
    f32_to_bf16_k<<<4096, 256, 0, stream>>>(x, xb, M * 1024 / 4);
    transpose_k<<<dim3(32, 32),  256, 0, stream>>>(Wq, wqkvT,                1024, 1024);
    transpose_k<<<dim3(32, 32),  256, 0, stream>>>(Wk, wqkvT + 1024 * 1024,  1024, 1024);
    transpose_k<<<dim3(32, 32),  256, 0, stream>>>(Wv, wqkvT + 2048 * 1024,  1024, 1024);
    transpose_k<<<dim3(32, 32),  256, 0, stream>>>(Wo, woT,                  1024, 1024);
    transpose_k<<<dim3(128, 32), 256, 0, stream>>>(W1, w1T, 1024, 4096);
    transpose_k<<<dim3(32, 128), 256, 0, stream>>>(W2, w2T, 4096, 1024);
    concat3_k<<<12, 256, 0, stream>>>(bq, bk, bv, bqkv);

    // QKV projection: (4096x1024) @ (1024x3072) -> qkv bf16
    gemm_bt<0><<<dim3(24, 32), 256, 0, stream>>>(xb, wqkvT, bqkv, nullptr, qkv, M, 3072, 1024);
    // attention -> ctx bf16
    attn_k<<<dim3(32, 32), 256, 0, stream>>>(qkv, mask, flag, ctxb);
    // attn_out + residual: r1 = ctx@Wo + bo + x  (f32)
    gemm_bt<2><<<dim3(8, 32), 256, 0, stream>>>(ctxb, woT, bo, x, r1f, M, 1024, 1024);
    // LN1 -> x1 (f32 + bf16)
    ln_k<1><<<4096, 256, 0, stream>>>(r1f, g1, be1, x1f, x1b);
    // FF1: relu(x1@W1 + b1) -> hb bf16 (4096x4096)
    gemm_bt<1><<<dim3(32, 32), 256, 0, stream>>>(x1b, w1T, b1, nullptr, hb, M, 4096, 1024);
    // FF2 + residual: r1 = hb@W2 + b2 + x1  (f32)
    gemm_bt<2><<<dim3(8, 32), 256, 0, stream>>>(hb, w2T, b2, x1f, r1f, M, 1024, 4096);
    // LN2 -> out
    ln_k<0><<<4096, 256, 0, stream>>>(r1f, g2, be2, (float*)d_out, nullptr);
}

// Round 2
// 1315.091 us; speedup vs baseline: 1.2149x; 1.2149x over previous
//
#include <hip/hip_runtime.h>
#include <stdint.h>

// ---------------------------------------------------------------------------
// HiSA transformer block on MI355X (gfx950), bf16-MFMA implementation.
// B=2, S=2048, D=1024, H=16, dk=64, F=4096.
// R2: bit-packed mask + global V^T => barrier-free flash-attention inner loop.
// ---------------------------------------------------------------------------

typedef __attribute__((ext_vector_type(8))) short short8;     // 8 bf16 (4 VGPRs)
typedef __attribute__((ext_vector_type(4))) float f32x4;      // MFMA C/D frag
typedef __attribute__((ext_vector_type(4))) unsigned short u16x4;

__device__ __forceinline__ unsigned short f2bf(float f) {
    union { float f; unsigned u; } v; v.f = f;
    unsigned r = v.u + 0x7fffu + ((v.u >> 16) & 1u);   // round-to-nearest-even
    return (unsigned short)(r >> 16);
}

// async global->LDS, 16B per lane. LDS dest must be wave-uniform base + lane*16.
__device__ __forceinline__ void gload16(const void* gsrc, void* ldst) {
    __builtin_amdgcn_global_load_lds(
        (const __attribute__((address_space(1))) void*)gsrc,
        (__attribute__((address_space(3))) void*)ldst,
        16, 0, 0);
}

// ---------------------------------------------------------------------------
// f32 -> bf16 elementwise convert (vectorized)
// ---------------------------------------------------------------------------
__global__ __launch_bounds__(256) void f32_to_bf16_k(
    const float* __restrict__ in, unsigned short* __restrict__ out, int n4)
{
    int i = blockIdx.x * 256 + threadIdx.x;
    if (i < n4) {
        f32x4 v = *(const f32x4*)&in[(size_t)i * 4];
        u16x4 o = { f2bf(v[0]), f2bf(v[1]), f2bf(v[2]), f2bf(v[3]) };
        *(u16x4*)&out[(size_t)i * 4] = o;
    }
}

// ---------------------------------------------------------------------------
// W (K x N, f32) -> Wt (N x K, bf16) tiled transpose
// ---------------------------------------------------------------------------
__global__ __launch_bounds__(256) void transpose_k(
    const float* __restrict__ W, unsigned short* __restrict__ Wt, int K, int N)
{
    __shared__ float tile[32][33];
    const int n0 = blockIdx.x * 32, k0 = blockIdx.y * 32;
    const int tx = threadIdx.x & 31, ty = threadIdx.x >> 5;  // ty in [0,8)
#pragma unroll
    for (int i = 0; i < 32; i += 8)
        tile[ty + i][tx] = W[(size_t)(k0 + ty + i) * N + n0 + tx];
    __syncthreads();
#pragma unroll
    for (int i = 0; i < 32; i += 8)
        Wt[(size_t)(n0 + ty + i) * K + k0 + tx] = f2bf(tile[tx][ty + i]);
}

// ---------------------------------------------------------------------------
// per-head V^T: vt[(bh*64 + d)*2048 + s] = V[b, s, h, d]
// qkv layout: row (b*2048+s) * 3072, V cols at 2048 + h*64 + d
// grid: (64 s-blocks, 2 d-blocks, 32 bh)
// ---------------------------------------------------------------------------
__global__ __launch_bounds__(256) void vtrans_k(
    const unsigned short* __restrict__ qkv, unsigned short* __restrict__ vt)
{
    __shared__ unsigned short tile[32][34];   // stride 34 shorts = 17 dwords (odd) -> conflict-free col reads
    const int s0 = blockIdx.x * 32;
    const int d0 = blockIdx.y * 32;
    const int bh = blockIdx.z, b = bh >> 4, h = bh & 15;
    const int tx = threadIdx.x & 31, ty = threadIdx.x >> 5;  // ty in [0,8)
#pragma unroll
    for (int i = 0; i < 32; i += 8)
        tile[ty + i][tx] = qkv[(size_t)(b * 2048 + s0 + ty + i) * 3072 + 2048 + h * 64 + d0 + tx];
    __syncthreads();
#pragma unroll
    for (int i = 0; i < 32; i += 8)
        vt[((size_t)bh * 64 + d0 + ty + i) * 2048 + s0 + tx] = tile[tx][ty + i];
}

// ---------------------------------------------------------------------------
// concat bq|bk|bv -> bqkv (3072)
// ---------------------------------------------------------------------------
__global__ void concat3_k(const float* a, const float* b, const float* c, float* out)
{
    int i = blockIdx.x * 256 + threadIdx.x;
    if (i < 3072) out[i] = (i < 1024) ? a[i] : (i < 2048 ? b[i - 1024] : c[i - 2048]);
}

// ---------------------------------------------------------------------------
// mask dtype detection: 0 = int32 0/1, 1 = packed bytes, 2 = f32 0/1
// (scan 64K words = 256KB; dtype is uniform across the buffer)
// ---------------------------------------------------------------------------
__global__ __launch_bounds__(1024) void detect_mask_k(
    const unsigned int* __restrict__ m, int* __restrict__ flag)
{
    __shared__ int f1, f2;
    if (threadIdx.x == 0) { f1 = 0; f2 = 0; }
    __syncthreads();
    int l1 = 0, l2 = 0;
    for (int i = threadIdx.x; i < 65536; i += 1024) {
        unsigned v = m[i];
        l1 |= (v > 1u);
        l2 |= (v != 0u && v != 0x3f800000u);
    }
    if (l1) atomicOr(&f1, 1);
    if (l2) atomicOr(&f2, 1);
    __syncthreads();
    if (threadIdx.x == 0) {
        int mode = 0;
        if (f1) mode = f2 ? 1 : 2;
        *flag = mode;
    }
}

// ---------------------------------------------------------------------------
// bit-pack mask: packed[i>>6] bit (i&63) = keep(element i)
// ---------------------------------------------------------------------------
__global__ __launch_bounds__(256) void pack_mask_k(
    const void* __restrict__ mask, const int* __restrict__ flag,
    unsigned long long* __restrict__ packed, long long nelem)
{
    const int mode = *flag;
    const long long stride = (long long)gridDim.x * 256;
    long long i = (long long)blockIdx.x * 256 + threadIdx.x;
    if (mode == 0) {
        const int* m = (const int*)mask;
        for (; i < nelem; i += stride) {
            unsigned long long bl = __ballot(m[i] != 0);
            if ((threadIdx.x & 63) == 0) packed[i >> 6] = bl;
        }
    } else if (mode == 1) {
        const unsigned char* m = (const unsigned char*)mask;
        for (; i < nelem; i += stride) {
            unsigned long long bl = __ballot(m[i] != 0);
            if ((threadIdx.x & 63) == 0) packed[i >> 6] = bl;
        }
    } else {
        const float* m = (const float*)mask;
        for (; i < nelem; i += stride) {
            unsigned long long bl = __ballot(m[i] != 0.f);
            if ((threadIdx.x & 63) == 0) packed[i >> 6] = bl;
        }
    }
}

// ---------------------------------------------------------------------------
// GEMM: C(M,N) = A(M,K)bf16 @ Bt(N,K)bf16^T + bias
//   EPI 0: store bf16
//   EPI 1: relu, store bf16
//   EPI 2: + resid(M,N f32), store f32
// 128x128 tile, BK=64, 256 threads (4 waves, 2x2), 16x16x32 bf16 MFMA.
// ---------------------------------------------------------------------------
template<int EPI>
__global__ __launch_bounds__(256) void gemm_bt(
    const unsigned short* __restrict__ A, const unsigned short* __restrict__ Bt,
    const float* __restrict__ bias, const float* __restrict__ resid,
    void* __restrict__ Cout, int M, int N, int K)
{
    __shared__ unsigned short As[128 * 64];
    __shared__ unsigned short Bs[128 * 64];
    const int t = threadIdx.x;
    const int lane = t & 63, wid = t >> 6;
    const int l16 = lane & 15, g = lane >> 4;
    const int wr = wid >> 1, wc = wid & 1;
    const int bm = blockIdx.y * 128, bn = blockIdx.x * 128;

    f32x4 acc[4][4] = {};

    for (int k0 = 0; k0 < K; k0 += 64) {
        __syncthreads();   // all waves done reading previous tile
#pragma unroll
        for (int i = 0; i < 4; ++i) {
            int linear = i * 2048 + t * 8;
            int row = linear >> 6, col = linear & 63;
            gload16(&A[(size_t)(bm + row) * K + k0 + col], &As[linear]);
        }
#pragma unroll
        for (int i = 0; i < 4; ++i) {
            int linear = i * 2048 + t * 8;
            int row = linear >> 6, col = linear & 63;
            gload16(&Bt[(size_t)(bn + row) * K + k0 + col], &Bs[linear]);
        }
        __syncthreads();   // drains vmcnt -> LDS tile valid
#pragma unroll
        for (int kc = 0; kc < 2; ++kc) {
            short8 a[4], b[4];
#pragma unroll
            for (int m = 0; m < 4; ++m)
                a[m] = *(const short8*)&As[(wr * 64 + m * 16 + l16) * 64 + kc * 32 + g * 8];
#pragma unroll
            for (int n = 0; n < 4; ++n)
                b[n] = *(const short8*)&Bs[(wc * 64 + n * 16 + l16) * 64 + kc * 32 + g * 8];
#pragma unroll
            for (int m = 0; m < 4; ++m)
#pragma unroll
                for (int n = 0; n < 4; ++n)
                    acc[m][n] = __builtin_amdgcn_mfma_f32_16x16x32_bf16(a[m], b[n], acc[m][n], 0, 0, 0);
        }
    }

    // epilogue: C row = bm + wr*64 + m*16 + g*4 + r ; col = bn + wc*64 + n*16 + l16
#pragma unroll
    for (int m = 0; m < 4; ++m) {
        const int row0 = bm + wr * 64 + m * 16 + g * 4;
#pragma unroll
        for (int n = 0; n < 4; ++n) {
            const int col = bn + wc * 64 + n * 16 + l16;
            const float bb = bias[col];
#pragma unroll
            for (int r = 0; r < 4; ++r) {
                float v = acc[m][n][r] + bb;
                const size_t idx = (size_t)(row0 + r) * N + col;
                if (EPI == 2) {
                    ((float*)Cout)[idx] = v + resid[idx];
                } else {
                    if (EPI == 1) v = fmaxf(v, 0.f);
                    ((unsigned short*)Cout)[idx] = f2bf(v);
                }
            }
        }
    }
}

// ---------------------------------------------------------------------------
// Flash attention, bit-packed mask, global V^T, barrier-free inner loop.
// qkv: (4096 rows) x 3072 bf16, cols [0,1024)=Q, [1024,2048)=K
// vt:  per-head V^T, (bh*64 + d) * 2048 + s
// pmask: bit i of word [(bh*2048+q)*32 + kt] = keep(q, kt*64 + i)
// grid: (S/64, B*H). block: 256 thr = 4 waves; wave w handles 16 q-rows.
// ---------------------------------------------------------------------------
__global__ __launch_bounds__(256) void attn_k(
    const unsigned short* __restrict__ qkv,
    const unsigned short* __restrict__ vt,
    const unsigned long long* __restrict__ pmask,
    unsigned short* __restrict__ ctx)
{
    __shared__ unsigned short Pl[4][16 * 72];     // per-wave P [q][kk]
    const int t = threadIdx.x, lane = t & 63, w = t >> 6;
    const int l16 = lane & 15, g = lane >> 4;
    const int bh = blockIdx.y;
    const int b = bh >> 4, h = bh & 15;
    const int q0 = blockIdx.x * 64;

    // Q fragments (A-operand): lane holds Q[q0+w*16+l16][g*8+e (+32c)]
    const size_t rowQ = (size_t)(b * 2048 + q0 + w * 16 + l16) * 3072 + h * 64;
    const short8 qf0 = *(const short8*)&qkv[rowQ + g * 8];
    const short8 qf1 = *(const short8*)&qkv[rowQ + 32 + g * 8];

    // packed-mask base for this thread's 4 q-rows (q = q0 + w*16 + g*4 + j)
    const unsigned long long* mbase =
        pmask + ((size_t)bh * 2048 + q0 + w * 16 + g * 4) * 32;
    const unsigned short* vbase = &vt[(size_t)bh * 64 * 2048];

    f32x4 acc[4] = {};
    float mrow[4], lrow[4];
#pragma unroll
    for (int j = 0; j < 4; ++j) { mrow[j] = -INFINITY; lrow[j] = 0.f; }

    for (int kt = 0; kt < 32; ++kt) {
        // mask words: one uint64 per q-row, broadcast across the 16-lane group
        unsigned long long mw[4];
#pragma unroll
        for (int j = 0; j < 4; ++j) mw[j] = mbase[j * 32 + kt];

        // S = Q K^T : 4 col-frags x 2 k-chunks (K direct from global, L1/L2-hit)
        f32x4 s[4] = {};
#pragma unroll
        for (int n = 0; n < 4; ++n) {
            const size_t rowK = (size_t)(b * 2048 + kt * 64 + n * 16 + l16) * 3072 + 1024 + h * 64;
            const short8 kf0 = *(const short8*)&qkv[rowK + g * 8];
            const short8 kf1 = *(const short8*)&qkv[rowK + 32 + g * 8];
            s[n] = __builtin_amdgcn_mfma_f32_16x16x32_bf16(qf0, kf0, s[n], 0, 0, 0);
            s[n] = __builtin_amdgcn_mfma_f32_16x16x32_bf16(qf1, kf1, s[n], 0, 0, 0);
        }

        // scale + mask. element: q-reg j, kk-bit = n*16 + l16
#pragma unroll
        for (int n = 0; n < 4; ++n) {
            const int sh = n * 16 + l16;
#pragma unroll
            for (int j = 0; j < 4; ++j) {
                const bool keep = (mw[j] >> sh) & 1ull;
                s[n][j] = keep ? s[n][j] * 0.125f : -1e30f;
            }
        }

        // online softmax per q-row (row = reg j within 16-lane group)
#pragma unroll
        for (int j = 0; j < 4; ++j) {
            float mx = fmaxf(fmaxf(s[0][j], s[1][j]), fmaxf(s[2][j], s[3][j]));
#pragma unroll
            for (int d = 1; d < 16; d <<= 1) mx = fmaxf(mx, __shfl_xor(mx, d));
            const float mn = fmaxf(mrow[j], mx);
            float p0 = __expf(s[0][j] - mn), p1 = __expf(s[1][j] - mn);
            float p2 = __expf(s[2][j] - mn), p3 = __expf(s[3][j] - mn);
            s[0][j] = p0; s[1][j] = p1; s[2][j] = p2; s[3][j] = p3;
            float sm = p0 + p1 + p2 + p3;
#pragma unroll
            for (int d = 1; d < 16; d <<= 1) sm += __shfl_xor(sm, d);
            const float scale = __expf(mrow[j] - mn);  // exp(-inf)=0 first tile
            lrow[j] = lrow[j] * scale + sm;
            mrow[j] = mn;
#pragma unroll
            for (int n = 0; n < 4; ++n) acc[n][j] *= scale;
        }

        // P (f32, C-layout) -> bf16 -> per-wave LDS [q][kk] (wave-local: no barrier)
#pragma unroll
        for (int n = 0; n < 4; ++n)
#pragma unroll
            for (int j = 0; j < 4; ++j)
                Pl[w][(g * 4 + j) * 72 + n * 16 + l16] = f2bf(s[n][j]);

        // O += P V : A = P from Pl, B = V^T rows direct from global
#pragma unroll
        for (int c = 0; c < 2; ++c) {
            const short8 pf = *(const short8*)&Pl[w][l16 * 72 + c * 32 + g * 8];
#pragma unroll
            for (int n = 0; n < 4; ++n) {
                const short8 vf = *(const short8*)&vbase[(size_t)(n * 16 + l16) * 2048 + kt * 64 + c * 32 + g * 8];
                acc[n] = __builtin_amdgcn_mfma_f32_16x16x32_bf16(pf, vf, acc[n], 0, 0, 0);
            }
        }
    }

    // epilogue: ctx[b*2048+q][h*64 + n*16 + l16] = acc/l
#pragma unroll
    for (int n = 0; n < 4; ++n)
#pragma unroll
        for (int j = 0; j < 4; ++j) {
            const int q = q0 + w * 16 + g * 4 + j;
            ctx[(size_t)(b * 2048 + q) * 1024 + h * 64 + n * 16 + l16] = f2bf(acc[n][j] / lrow[j]);
        }
}

// ---------------------------------------------------------------------------
// row LayerNorm over 1024. WB=1: also write bf16 copy.
// ---------------------------------------------------------------------------
template<int WB>
__global__ __launch_bounds__(256) void ln_k(
    const float* __restrict__ in, const float* __restrict__ gw, const float* __restrict__ bw,
    float* __restrict__ outF, unsigned short* __restrict__ outB)
{
    __shared__ float red[2][4];
    const int row = blockIdx.x, t = threadIdx.x;
    const f32x4 v = *(const f32x4*)&in[(size_t)row * 1024 + t * 4];
    float s = v[0] + v[1] + v[2] + v[3];
    float ss = v[0] * v[0] + v[1] * v[1] + v[2] * v[2] + v[3] * v[3];
#pragma unroll
    for (int d = 1; d < 64; d <<= 1) { s += __shfl_xor(s, d); ss += __shfl_xor(ss, d); }
    if ((t & 63) == 0) { red[0][t >> 6] = s; red[1][t >> 6] = ss; }
    __syncthreads();
    s = red[0][0] + red[0][1] + red[0][2] + red[0][3];
    ss = red[1][0] + red[1][1] + red[1][2] + red[1][3];
    const float mu = s * (1.f / 1024.f);
    const float var = ss * (1.f / 1024.f) - mu * mu;
    const float rs = rsqrtf(var + 1e-5f);
    f32x4 y;
#pragma unroll
    for (int e = 0; e < 4; ++e)
        y[e] = (v[e] - mu) * rs * gw[t * 4 + e] + bw[t * 4 + e];
    *(f32x4*)&outF[(size_t)row * 1024 + t * 4] = y;
    if (WB) {
        u16x4 o = { f2bf(y[0]), f2bf(y[1]), f2bf(y[2]), f2bf(y[3]) };
        *(u16x4*)&outB[(size_t)row * 1024 + t * 4] = o;
    }
}

// ---------------------------------------------------------------------------
extern "C" void kernel_launch(void* const* d_in, const int* in_sizes, int n_in,
                              void* d_out, int out_size, void* d_ws, size_t ws_size,
                              hipStream_t stream)
{
    (void)n_in; (void)out_size; (void)ws_size;
    const float* x   = (const float*)d_in[0];
    const void*  mask = d_in[1];
    const float* Wq  = (const float*)d_in[2];
    const float* bq  = (const float*)d_in[3];
    const float* Wk  = (const float*)d_in[4];
    const float* bk  = (const float*)d_in[5];
    const float* Wv  = (const float*)d_in[6];
    const float* bv  = (const float*)d_in[7];
    const float* Wo  = (const float*)d_in[8];
    const float* bo  = (const float*)d_in[9];
    const float* g1  = (const float*)d_in[10];
    const float* be1 = (const float*)d_in[11];
    const float* g2  = (const float*)d_in[12];
    const float* be2 = (const float*)d_in[13];
    const float* W1  = (const float*)d_in[14];
    const float* b1  = (const float*)d_in[15];
    const float* W2  = (const float*)d_in[16];
    const float* b2  = (const float*)d_in[17];

    const int M = 4096;   // B*S
    const long long maskN = in_sizes[1];   // 134217728

    char* wsb = (char*)d_ws;
    size_t off = 0;
    auto alloc = [&](size_t bytes) -> char* {
        char* p = wsb + off;
        off += (bytes + 255) & ~(size_t)255;
        return p;
    };
    int*            flag   = (int*)           alloc(256);
    unsigned long long* pm = (unsigned long long*)alloc((size_t)(maskN / 64) * 8);
    unsigned short* xb     = (unsigned short*)alloc((size_t)M * 1024 * 2);
    unsigned short* wqkvT  = (unsigned short*)alloc((size_t)3072 * 1024 * 2);
    unsigned short* woT    = (unsigned short*)alloc((size_t)1024 * 1024 * 2);
    unsigned short* w1T    = (unsigned short*)alloc((size_t)4096 * 1024 * 2);
    unsigned short* w2T    = (unsigned short*)alloc((size_t)1024 * 4096 * 2);
    float*          bqkv   = (float*)         alloc(3072 * 4);
    unsigned short* qkv    = (unsigned short*)alloc((size_t)M * 3072 * 2);
    unsigned short* vtb    = (unsigned short*)alloc((size_t)32 * 64 * 2048 * 2);
    unsigned short* ctxb   = (unsigned short*)alloc((size_t)M * 1024 * 2);
    float*          r1f    = (float*)         alloc((size_t)M * 1024 * 4);
    float*          x1f    = (float*)         alloc((size_t)M * 1024 * 4);
    unsigned short* x1b    = (unsigned short*)alloc((size_t)M * 1024 * 2);
    unsigned short* hb     = (unsigned short*)alloc((size_t)M * 4096 * 2);
    // total ~168 MB

    detect_mask_k<<<1, 1024, 0, stream>>>((const unsigned int*)mask, flag);
    pack_mask_k<<<2048, 256, 0, stream>>>(mask, flag, pm, maskN);
    f32_to_bf16_k<<<4096, 256, 0, stream>>>(x, xb, M * 1024 / 4);
    transpose_k<<<dim3(32, 32),  256, 0, stream>>>(Wq, wqkvT,                1024, 1024);
    transpose_k<<<dim3(32, 32),  256, 0, stream>>>(Wk, wqkvT + 1024 * 1024,  1024, 1024);
    transpose_k<<<dim3(32, 32),  256, 0, stream>>>(Wv, wqkvT + 2048 * 1024,  1024, 1024);
    transpose_k<<<dim3(32, 32),  256, 0, stream>>>(Wo, woT,                  1024, 1024);
    transpose_k<<<dim3(128, 32), 256, 0, stream>>>(W1, w1T, 1024, 4096);
    transpose_k<<<dim3(32, 128), 256, 0, stream>>>(W2, w2T, 4096, 1024);
    concat3_k<<<12, 256, 0, stream>>>(bq, bk, bv, bqkv);

    // QKV projection: (4096x1024) @ (1024x3072) -> qkv bf16
    gemm_bt<0><<<dim3(24, 32), 256, 0, stream>>>(xb, wqkvT, bqkv, nullptr, qkv, M, 3072, 1024);
    // per-head V^T
    vtrans_k<<<dim3(64, 2, 32), 256, 0, stream>>>(qkv, vtb);
    // attention -> ctx bf16
    attn_k<<<dim3(32, 32), 256, 0, stream>>>(qkv, vtb, pm, ctxb);
    // attn_out + residual: r1 = ctx@Wo + bo + x  (f32)
    gemm_bt<2><<<dim3(8, 32), 256, 0, stream>>>(ctxb, woT, bo, x, r1f, M, 1024, 1024);
    // LN1 -> x1 (f32 + bf16)
    ln_k<1><<<4096, 256, 0, stream>>>(r1f, g1, be1, x1f, x1b);
    // FF1: relu(x1@W1 + b1) -> hb bf16 (4096x4096)
    gemm_bt<1><<<dim3(32, 32), 256, 0, stream>>>(x1b, w1T, b1, nullptr, hb, M, 4096, 1024);
    // FF2 + residual: r1 = hb@W2 + b2 + x1  (f32)
    gemm_bt<2><<<dim3(8, 32), 256, 0, stream>>>(hb, w2T, b2, x1f, r1f, M, 1024, 4096);
    // LN2 -> out
    ln_k<0><<<4096, 256, 0, stream>>>(r1f, g2, be2, (float*)d_out, nullptr);
}

// Round 3
// 1294.982 us; speedup vs baseline: 1.2338x; 1.0155x over previous
//
#include <hip/hip_runtime.h>
#include <stdint.h>

// ---------------------------------------------------------------------------
// HiSA transformer block on MI355X (gfx950), bf16-MFMA implementation.
// B=2, S=2048, D=1024, H=16, dk=64, F=4096.
// R3: QKV + FF1 GEMMs ported to 256x256 8-phase template (T1+T2+T3+T4+T5).
// ---------------------------------------------------------------------------

typedef __attribute__((ext_vector_type(8))) short short8;     // 8 bf16 (4 VGPRs)
typedef __attribute__((ext_vector_type(4))) float f32x4;      // MFMA C/D frag
typedef __attribute__((ext_vector_type(4))) unsigned short u16x4;

__device__ __forceinline__ unsigned short f2bf(float f) {
    union { float f; unsigned u; } v; v.f = f;
    unsigned r = v.u + 0x7fffu + ((v.u >> 16) & 1u);   // round-to-nearest-even
    return (unsigned short)(r >> 16);
}

// async global->LDS, 16B per lane. LDS dest must be wave-uniform base + lane*16.
__device__ __forceinline__ void gload16(const void* gsrc, void* ldst) {
    __builtin_amdgcn_global_load_lds(
        (const __attribute__((address_space(1))) void*)gsrc,
        (__attribute__((address_space(3))) void*)ldst,
        16, 0, 0);
}

// st_16x32 XOR swizzle: toggle byte-bit5 with byte-bit9 (within 1KB subtile)
__device__ __forceinline__ int SWZ(int b) { return b ^ (((b >> 9) & 1) << 5); }

// ---------------------------------------------------------------------------
// f32 -> bf16 elementwise convert (vectorized)
// ---------------------------------------------------------------------------
__global__ __launch_bounds__(256) void f32_to_bf16_k(
    const float* __restrict__ in, unsigned short* __restrict__ out, int n4)
{
    int i = blockIdx.x * 256 + threadIdx.x;
    if (i < n4) {
        f32x4 v = *(const f32x4*)&in[(size_t)i * 4];
        u16x4 o = { f2bf(v[0]), f2bf(v[1]), f2bf(v[2]), f2bf(v[3]) };
        *(u16x4*)&out[(size_t)i * 4] = o;
    }
}

// ---------------------------------------------------------------------------
// W (K x N, f32) -> Wt (N x K, bf16) tiled transpose
// ---------------------------------------------------------------------------
__global__ __launch_bounds__(256) void transpose_k(
    const float* __restrict__ W, unsigned short* __restrict__ Wt, int K, int N)
{
    __shared__ float tile[32][33];
    const int n0 = blockIdx.x * 32, k0 = blockIdx.y * 32;
    const int tx = threadIdx.x & 31, ty = threadIdx.x >> 5;  // ty in [0,8)
#pragma unroll
    for (int i = 0; i < 32; i += 8)
        tile[ty + i][tx] = W[(size_t)(k0 + ty + i) * N + n0 + tx];
    __syncthreads();
#pragma unroll
    for (int i = 0; i < 32; i += 8)
        Wt[(size_t)(n0 + ty + i) * K + k0 + tx] = f2bf(tile[tx][ty + i]);
}

// ---------------------------------------------------------------------------
// per-head V^T: vt[(bh*64 + d)*2048 + s] = V[b, s, h, d]
// ---------------------------------------------------------------------------
__global__ __launch_bounds__(256) void vtrans_k(
    const unsigned short* __restrict__ qkv, unsigned short* __restrict__ vt)
{
    __shared__ unsigned short tile[32][34];
    const int s0 = blockIdx.x * 32;
    const int d0 = blockIdx.y * 32;
    const int bh = blockIdx.z, b = bh >> 4, h = bh & 15;
    const int tx = threadIdx.x & 31, ty = threadIdx.x >> 5;
#pragma unroll
    for (int i = 0; i < 32; i += 8)
        tile[ty + i][tx] = qkv[(size_t)(b * 2048 + s0 + ty + i) * 3072 + 2048 + h * 64 + d0 + tx];
    __syncthreads();
#pragma unroll
    for (int i = 0; i < 32; i += 8)
        vt[((size_t)bh * 64 + d0 + ty + i) * 2048 + s0 + tx] = tile[tx][ty + i];
}

// ---------------------------------------------------------------------------
__global__ void concat3_k(const float* a, const float* b, const float* c, float* out)
{
    int i = blockIdx.x * 256 + threadIdx.x;
    if (i < 3072) out[i] = (i < 1024) ? a[i] : (i < 2048 ? b[i - 1024] : c[i - 2048]);
}

// ---------------------------------------------------------------------------
// mask dtype detection: 0 = int32 0/1, 1 = packed bytes, 2 = f32 0/1
// ---------------------------------------------------------------------------
__global__ __launch_bounds__(1024) void detect_mask_k(
    const unsigned int* __restrict__ m, int* __restrict__ flag)
{
    __shared__ int f1, f2;
    if (threadIdx.x == 0) { f1 = 0; f2 = 0; }
    __syncthreads();
    int l1 = 0, l2 = 0;
    for (int i = threadIdx.x; i < 65536; i += 1024) {
        unsigned v = m[i];
        l1 |= (v > 1u);
        l2 |= (v != 0u && v != 0x3f800000u);
    }
    if (l1) atomicOr(&f1, 1);
    if (l2) atomicOr(&f2, 1);
    __syncthreads();
    if (threadIdx.x == 0) {
        int mode = 0;
        if (f1) mode = f2 ? 1 : 2;
        *flag = mode;
    }
}

// ---------------------------------------------------------------------------
// bit-pack mask
// ---------------------------------------------------------------------------
__global__ __launch_bounds__(256) void pack_mask_k(
    const void* __restrict__ mask, const int* __restrict__ flag,
    unsigned long long* __restrict__ packed, long long nelem)
{
    const int mode = *flag;
    const long long stride = (long long)gridDim.x * 256;
    long long i = (long long)blockIdx.x * 256 + threadIdx.x;
    if (mode == 0) {
        const int* m = (const int*)mask;
        for (; i < nelem; i += stride) {
            unsigned long long bl = __ballot(m[i] != 0);
            if ((threadIdx.x & 63) == 0) packed[i >> 6] = bl;
        }
    } else if (mode == 1) {
        const unsigned char* m = (const unsigned char*)mask;
        for (; i < nelem; i += stride) {
            unsigned long long bl = __ballot(m[i] != 0);
            if ((threadIdx.x & 63) == 0) packed[i >> 6] = bl;
        }
    } else {
        const float* m = (const float*)mask;
        for (; i < nelem; i += stride) {
            unsigned long long bl = __ballot(m[i] != 0.f);
            if ((threadIdx.x & 63) == 0) packed[i >> 6] = bl;
        }
    }
}

// ---------------------------------------------------------------------------
// 256x256 8-phase GEMM (T1+T2+T3+T4+T5): C(M,N) = A(M,K) @ Bt(N,K)^T + bias
//   EPI 0: store bf16.  EPI 1: relu, store bf16.
// 512 threads = 8 waves (2M x 4N), BK=64, LDS 128 KiB double-buffered,
// st_16x32 swizzle, counted vmcnt(4) at phases 4/8 only, setprio around MFMA.
// Requires M%256==0, N%256==0, K%128==0.
// ---------------------------------------------------------------------------
template<int EPI>
__global__ __launch_bounds__(512) void gemm256_bt(
    const unsigned short* __restrict__ A, const unsigned short* __restrict__ Bt,
    const float* __restrict__ bias, void* __restrict__ Cout,
    int M, int N, int K)
{
    // [dbuf][A/B][256 rows][64 cols] bf16 = 128 KiB
    __shared__ __align__(16) unsigned short lds[2][2][256 * 64];
    const int t = threadIdx.x;
    const int lane = t & 63;
    const int wid = t >> 6;
    const int l16 = lane & 15, g = lane >> 4;
    const int wr = wid >> 2, wc = wid & 3;   // 2M x 4N wave grid

    // T1: bijective XCD swizzle on linear block id (m204 formula, NXCD=8)
    const int nbx = gridDim.x, nwg = nbx * gridDim.y;
    const int orig = blockIdx.y * nbx + blockIdx.x;
    const int qq = nwg >> 3, rr = nwg & 7;
    const int xcd = orig & 7, idx = orig >> 3;
    const int wg = (xcd < rr) ? (xcd * (qq + 1) + idx)
                              : (rr * (qq + 1) + (xcd - rr) * qq + idx);
    const int bm = (wg / nbx) * 256, bn = (wg % nbx) * 256;

    const int ntiles = K >> 6;
    auto kof = [&](int s) { return (s < ntiles ? s : ntiles - 1) << 6; };

    // stage one half-tile (128 rows x 64 cols) of A or B into LDS.
    // LDS dest is linear (wave-uniform base + lane*16); global source is
    // pre-swizzled so that a SWZ'd read returns the right element.
    auto stage_half = [&](const unsigned short* __restrict__ P, int grow0, int k0,
                          int buf, int ab, int half) {
#pragma unroll
        for (int rnd = 0; rnd < 2; ++rnd) {
            const int off = rnd * 8192 + t * 16;        // byte offset in 16 KiB half
            const int sw  = SWZ(off);
            const int row = off >> 7;                   // 0..127
            const int col = (sw & 127) >> 1;            // bf16 col 0..63
            gload16(&P[(size_t)(grow0 + half * 128 + row) * K + k0 + col],
                    &lds[buf][ab][half * 8192 + (off >> 1)]);
        }
    };

    // swizzled fragment reads
    auto lda = [&](int buf, int m, int kc) -> short8 {
        const int byte = ((m * 32 + wr * 16 + l16) * 64 + kc * 32 + g * 8) * 2;
        return *(const short8*)((const char*)&lds[buf][0][0] + SWZ(byte));
    };
    auto ldb = [&](int buf, int n, int kc) -> short8 {
        const int byte = ((n * 64 + wc * 16 + l16) * 64 + kc * 32 + g * 8) * 2;
        return *(const short8*)((const char*)&lds[buf][1][0] + SWZ(byte));
    };

    f32x4 acc[8][4] = {};
    short8 af[4][2];

    // prologue: tile0 (all 4 halves) -> buf0 ; tile1 A0,B0 -> buf1
    stage_half(A,  bm, 0,  0, 0, 0);
    stage_half(A,  bm, 0,  0, 0, 1);
    stage_half(Bt, bn, 0,  0, 1, 0);
    stage_half(Bt, bn, 0,  0, 1, 1);
    stage_half(A,  bm, 64, 1, 0, 0);
    stage_half(Bt, bn, 64, 1, 1, 0);
    asm volatile("s_waitcnt vmcnt(4)" ::: "memory");   // tile0 resident
    __builtin_amdgcn_s_barrier();

#define PH(buf, mh, nh, doLoadA, STAGE_STMT, doVM)                                  \
  {                                                                                  \
    if (doLoadA) {                                                                   \
      _Pragma("unroll") for (int mm = 0; mm < 4; ++mm)                               \
      _Pragma("unroll") for (int kc = 0; kc < 2; ++kc)                               \
        af[mm][kc] = lda(buf, (mh) * 4 + mm, kc);                                    \
    }                                                                                \
    short8 bf[2][2];                                                                 \
    _Pragma("unroll") for (int nn = 0; nn < 2; ++nn)                                 \
    _Pragma("unroll") for (int kc = 0; kc < 2; ++kc)                                 \
      bf[nn][kc] = ldb(buf, (nh) * 2 + nn, kc);                                      \
    STAGE_STMT;                                                                      \
    __builtin_amdgcn_s_barrier();                                                    \
    __builtin_amdgcn_s_setprio(1);                                                   \
    _Pragma("unroll") for (int mm = 0; mm < 4; ++mm)                                 \
    _Pragma("unroll") for (int nn = 0; nn < 2; ++nn)                                 \
    _Pragma("unroll") for (int kc = 0; kc < 2; ++kc)                                 \
      acc[(mh) * 4 + mm][(nh) * 2 + nn] = __builtin_amdgcn_mfma_f32_16x16x32_bf16(   \
          af[mm][kc], bf[nn][kc], acc[(mh) * 4 + mm][(nh) * 2 + nn], 0, 0, 0);       \
    __builtin_amdgcn_s_setprio(0);                                                   \
    if (doVM) { asm volatile("s_waitcnt vmcnt(4)" ::: "memory"); }                   \
    __builtin_amdgcn_s_barrier();                                                    \
  }

    // iteration i computes tiles 2i (buf0, ph1-4) and 2i+1 (buf1, ph5-8).
    // staging schedule (each half lands >=1 phase after its last reader):
    //  ph1: buf1.A1 <- t(2i+1)   ph2: buf1.B1 <- t(2i+1)
    //  ph3: buf0.A0 <- t(2i+2)   ph4: buf0.B0 <- t(2i+2)  [vmcnt(4)]
    //  ph5: buf0.A1 <- t(2i+2)   ph6: buf0.B1 <- t(2i+2)
    //  ph7: buf1.A0 <- t(2i+3)   ph8: buf1.B0 <- t(2i+3)  [vmcnt(4)]
    const int half_ntiles = ntiles >> 1;
    for (int i = 0; i < half_ntiles; ++i) {
        const int k1 = (2 * i + 1) << 6;
        const int k2 = kof(2 * i + 2);
        const int k3 = kof(2 * i + 3);
        PH(0, 0, 0, 1, (stage_half(A,  bm, k1, 1, 0, 1)), 0)
        PH(0, 0, 1, 0, (stage_half(Bt, bn, k1, 1, 1, 1)), 0)
        PH(0, 1, 0, 1, (stage_half(A,  bm, k2, 0, 0, 0)), 0)
        PH(0, 1, 1, 0, (stage_half(Bt, bn, k2, 0, 1, 0)), 1)
        PH(1, 0, 0, 1, (stage_half(A,  bm, k2, 0, 0, 1)), 0)
        PH(1, 0, 1, 0, (stage_half(Bt, bn, k2, 0, 1, 1)), 0)
        PH(1, 1, 0, 1, (stage_half(A,  bm, k3, 1, 0, 0)), 0)
        PH(1, 1, 1, 0, (stage_half(Bt, bn, k3, 1, 1, 0)), 1)
    }
#undef PH

    // epilogue: C row = bm + m*32 + wr*16 + g*4 + r ; col = bn + n*64 + wc*16 + l16
#pragma unroll
    for (int m = 0; m < 8; ++m) {
        const int row0 = bm + m * 32 + wr * 16 + g * 4;
#pragma unroll
        for (int n = 0; n < 4; ++n) {
            const int col = bn + n * 64 + wc * 16 + l16;
            const float bb = bias[col];
#pragma unroll
            for (int r = 0; r < 4; ++r) {
                float v = acc[m][n][r] + bb;
                if (EPI == 1) v = fmaxf(v, 0.f);
                ((unsigned short*)Cout)[(size_t)(row0 + r) * N + col] = f2bf(v);
            }
        }
    }
}

// ---------------------------------------------------------------------------
// 128x128 GEMM (m97 structure): used for Wo and FF2 (EPI 2: +resid, f32 out)
// ---------------------------------------------------------------------------
template<int EPI>
__global__ __launch_bounds__(256) void gemm_bt(
    const unsigned short* __restrict__ A, const unsigned short* __restrict__ Bt,
    const float* __restrict__ bias, const float* __restrict__ resid,
    void* __restrict__ Cout, int M, int N, int K)
{
    __shared__ unsigned short As[128 * 64];
    __shared__ unsigned short Bs[128 * 64];
    const int t = threadIdx.x;
    const int lane = t & 63, wid = t >> 6;
    const int l16 = lane & 15, g = lane >> 4;
    const int wr = wid >> 1, wc = wid & 1;
    const int bm = blockIdx.y * 128, bn = blockIdx.x * 128;

    f32x4 acc[4][4] = {};

    for (int k0 = 0; k0 < K; k0 += 64) {
        __syncthreads();
#pragma unroll
        for (int i = 0; i < 4; ++i) {
            int linear = i * 2048 + t * 8;
            int row = linear >> 6, col = linear & 63;
            gload16(&A[(size_t)(bm + row) * K + k0 + col], &As[linear]);
        }
#pragma unroll
        for (int i = 0; i < 4; ++i) {
            int linear = i * 2048 + t * 8;
            int row = linear >> 6, col = linear & 63;
            gload16(&Bt[(size_t)(bn + row) * K + k0 + col], &Bs[linear]);
        }
        __syncthreads();
#pragma unroll
        for (int kc = 0; kc < 2; ++kc) {
            short8 a[4], b[4];
#pragma unroll
            for (int m = 0; m < 4; ++m)
                a[m] = *(const short8*)&As[(wr * 64 + m * 16 + l16) * 64 + kc * 32 + g * 8];
#pragma unroll
            for (int n = 0; n < 4; ++n)
                b[n] = *(const short8*)&Bs[(wc * 64 + n * 16 + l16) * 64 + kc * 32 + g * 8];
#pragma unroll
            for (int m = 0; m < 4; ++m)
#pragma unroll
                for (int n = 0; n < 4; ++n)
                    acc[m][n] = __builtin_amdgcn_mfma_f32_16x16x32_bf16(a[m], b[n], acc[m][n], 0, 0, 0);
        }
    }

#pragma unroll
    for (int m = 0; m < 4; ++m) {
        const int row0 = bm + wr * 64 + m * 16 + g * 4;
#pragma unroll
        for (int n = 0; n < 4; ++n) {
            const int col = bn + wc * 64 + n * 16 + l16;
            const float bb = bias[col];
#pragma unroll
            for (int r = 0; r < 4; ++r) {
                float v = acc[m][n][r] + bb;
                const size_t idx = (size_t)(row0 + r) * N + col;
                if (EPI == 2) {
                    ((float*)Cout)[idx] = v + resid[idx];
                } else {
                    if (EPI == 1) v = fmaxf(v, 0.f);
                    ((unsigned short*)Cout)[idx] = f2bf(v);
                }
            }
        }
    }
}

// ---------------------------------------------------------------------------
// Flash attention, bit-packed mask, global V^T, barrier-free inner loop.
// ---------------------------------------------------------------------------
__global__ __launch_bounds__(256) void attn_k(
    const unsigned short* __restrict__ qkv,
    const unsigned short* __restrict__ vt,
    const unsigned long long* __restrict__ pmask,
    unsigned short* __restrict__ ctx)
{
    __shared__ unsigned short Pl[4][16 * 72];
    const int t = threadIdx.x, lane = t & 63, w = t >> 6;
    const int l16 = lane & 15, g = lane >> 4;
    const int bh = blockIdx.y;
    const int b = bh >> 4, h = bh & 15;
    const int q0 = blockIdx.x * 64;

    const size_t rowQ = (size_t)(b * 2048 + q0 + w * 16 + l16) * 3072 + h * 64;
    const short8 qf0 = *(const short8*)&qkv[rowQ + g * 8];
    const short8 qf1 = *(const short8*)&qkv[rowQ + 32 + g * 8];

    const unsigned long long* mbase =
        pmask + ((size_t)bh * 2048 + q0 + w * 16 + g * 4) * 32;
    const unsigned short* vbase = &vt[(size_t)bh * 64 * 2048];

    f32x4 acc[4] = {};
    float mrow[4], lrow[4];
#pragma unroll
    for (int j = 0; j < 4; ++j) { mrow[j] = -INFINITY; lrow[j] = 0.f; }

    for (int kt = 0; kt < 32; ++kt) {
        unsigned long long mw[4];
#pragma unroll
        for (int j = 0; j < 4; ++j) mw[j] = mbase[j * 32 + kt];

        f32x4 s[4] = {};
#pragma unroll
        for (int n = 0; n < 4; ++n) {
            const size_t rowK = (size_t)(b * 2048 + kt * 64 + n * 16 + l16) * 3072 + 1024 + h * 64;
            const short8 kf0 = *(const short8*)&qkv[rowK + g * 8];
            const short8 kf1 = *(const short8*)&qkv[rowK + 32 + g * 8];
            s[n] = __builtin_amdgcn_mfma_f32_16x16x32_bf16(qf0, kf0, s[n], 0, 0, 0);
            s[n] = __builtin_amdgcn_mfma_f32_16x16x32_bf16(qf1, kf1, s[n], 0, 0, 0);
        }

#pragma unroll
        for (int n = 0; n < 4; ++n) {
            const int sh = n * 16 + l16;
#pragma unroll
            for (int j = 0; j < 4; ++j) {
                const bool keep = (mw[j] >> sh) & 1ull;
                s[n][j] = keep ? s[n][j] * 0.125f : -1e30f;
            }
        }

#pragma unroll
        for (int j = 0; j < 4; ++j) {
            float mx = fmaxf(fmaxf(s[0][j], s[1][j]), fmaxf(s[2][j], s[3][j]));
#pragma unroll
            for (int d = 1; d < 16; d <<= 1) mx = fmaxf(mx, __shfl_xor(mx, d));
            const float mn = fmaxf(mrow[j], mx);
            float p0 = __expf(s[0][j] - mn), p1 = __expf(s[1][j] - mn);
            float p2 = __expf(s[2][j] - mn), p3 = __expf(s[3][j] - mn);
            s[0][j] = p0; s[1][j] = p1; s[2][j] = p2; s[3][j] = p3;
            float sm = p0 + p1 + p2 + p3;
#pragma unroll
            for (int d = 1; d < 16; d <<= 1) sm += __shfl_xor(sm, d);
            const float scale = __expf(mrow[j] - mn);
            lrow[j] = lrow[j] * scale + sm;
            mrow[j] = mn;
#pragma unroll
            for (int n = 0; n < 4; ++n) acc[n][j] *= scale;
        }

#pragma unroll
        for (int n = 0; n < 4; ++n)
#pragma unroll
            for (int j = 0; j < 4; ++j)
                Pl[w][(g * 4 + j) * 72 + n * 16 + l16] = f2bf(s[n][j]);

#pragma unroll
        for (int c = 0; c < 2; ++c) {
            const short8 pf = *(const short8*)&Pl[w][l16 * 72 + c * 32 + g * 8];
#pragma unroll
            for (int n = 0; n < 4; ++n) {
                const short8 vf = *(const short8*)&vbase[(size_t)(n * 16 + l16) * 2048 + kt * 64 + c * 32 + g * 8];
                acc[n] = __builtin_amdgcn_mfma_f32_16x16x32_bf16(pf, vf, acc[n], 0, 0, 0);
            }
        }
    }

#pragma unroll
    for (int n = 0; n < 4; ++n)
#pragma unroll
        for (int j = 0; j < 4; ++j) {
            const int q = q0 + w * 16 + g * 4 + j;
            ctx[(size_t)(b * 2048 + q) * 1024 + h * 64 + n * 16 + l16] = f2bf(acc[n][j] / lrow[j]);
        }
}

// ---------------------------------------------------------------------------
// row LayerNorm over 1024. WB=1: also write bf16 copy.
// ---------------------------------------------------------------------------
template<int WB>
__global__ __launch_bounds__(256) void ln_k(
    const float* __restrict__ in, const float* __restrict__ gw, const float* __restrict__ bw,
    float* __restrict__ outF, unsigned short* __restrict__ outB)
{
    __shared__ float red[2][4];
    const int row = blockIdx.x, t = threadIdx.x;
    const f32x4 v = *(const f32x4*)&in[(size_t)row * 1024 + t * 4];
    float s = v[0] + v[1] + v[2] + v[3];
    float ss = v[0] * v[0] + v[1] * v[1] + v[2] * v[2] + v[3] * v[3];
#pragma unroll
    for (int d = 1; d < 64; d <<= 1) { s += __shfl_xor(s, d); ss += __shfl_xor(ss, d); }
    if ((t & 63) == 0) { red[0][t >> 6] = s; red[1][t >> 6] = ss; }
    __syncthreads();
    s = red[0][0] + red[0][1] + red[0][2] + red[0][3];
    ss = red[1][0] + red[1][1] + red[1][2] + red[1][3];
    const float mu = s * (1.f / 1024.f);
    const float var = ss * (1.f / 1024.f) - mu * mu;
    const float rs = rsqrtf(var + 1e-5f);
    f32x4 y;
#pragma unroll
    for (int e = 0; e < 4; ++e)
        y[e] = (v[e] - mu) * rs * gw[t * 4 + e] + bw[t * 4 + e];
    *(f32x4*)&outF[(size_t)row * 1024 + t * 4] = y;
    if (WB) {
        u16x4 o = { f2bf(y[0]), f2bf(y[1]), f2bf(y[2]), f2bf(y[3]) };
        *(u16x4*)&outB[(size_t)row * 1024 + t * 4] = o;
    }
}

// ---------------------------------------------------------------------------
extern "C" void kernel_launch(void* const* d_in, const int* in_sizes, int n_in,
                              void* d_out, int out_size, void* d_ws, size_t ws_size,
                              hipStream_t stream)
{
    (void)n_in; (void)out_size; (void)ws_size;
    const float* x   = (const float*)d_in[0];
    const void*  mask = d_in[1];
    const float* Wq  = (const float*)d_in[2];
    const float* bq  = (const float*)d_in[3];
    const float* Wk  = (const float*)d_in[4];
    const float* bk  = (const float*)d_in[5];
    const float* Wv  = (const float*)d_in[6];
    const float* bv  = (const float*)d_in[7];
    const float* Wo  = (const float*)d_in[8];
    const float* bo  = (const float*)d_in[9];
    const float* g1  = (const float*)d_in[10];
    const float* be1 = (const float*)d_in[11];
    const float* g2  = (const float*)d_in[12];
    const float* be2 = (const float*)d_in[13];
    const float* W1  = (const float*)d_in[14];
    const float* b1  = (const float*)d_in[15];
    const float* W2  = (const float*)d_in[16];
    const float* b2  = (const float*)d_in[17];

    const int M = 4096;   // B*S
    const long long maskN = in_sizes[1];

    char* wsb = (char*)d_ws;
    size_t off = 0;
    auto alloc = [&](size_t bytes) -> char* {
        char* p = wsb + off;
        off += (bytes + 255) & ~(size_t)255;
        return p;
    };
    int*            flag   = (int*)           alloc(256);
    unsigned long long* pm = (unsigned long long*)alloc((size_t)(maskN / 64) * 8);
    unsigned short* xb     = (unsigned short*)alloc((size_t)M * 1024 * 2);
    unsigned short* wqkvT  = (unsigned short*)alloc((size_t)3072 * 1024 * 2);
    unsigned short* woT    = (unsigned short*)alloc((size_t)1024 * 1024 * 2);
    unsigned short* w1T    = (unsigned short*)alloc((size_t)4096 * 1024 * 2);
    unsigned short* w2T    = (unsigned short*)alloc((size_t)1024 * 4096 * 2);
    float*          bqkv   = (float*)         alloc(3072 * 4);
    unsigned short* qkv    = (unsigned short*)alloc((size_t)M * 3072 * 2);
    unsigned short* vtb    = (unsigned short*)alloc((size_t)32 * 64 * 2048 * 2);
    unsigned short* ctxb   = (unsigned short*)alloc((size_t)M * 1024 * 2);
    float*          r1f    = (float*)         alloc((size_t)M * 1024 * 4);
    float*          x1f    = (float*)         alloc((size_t)M * 1024 * 4);
    unsigned short* x1b    = (unsigned short*)alloc((size_t)M * 1024 * 2);
    unsigned short* hb     = (unsigned short*)alloc((size_t)M * 4096 * 2);

    detect_mask_k<<<1, 1024, 0, stream>>>((const unsigned int*)mask, flag);
    pack_mask_k<<<2048, 256, 0, stream>>>(mask, flag, pm, maskN);
    f32_to_bf16_k<<<4096, 256, 0, stream>>>(x, xb, M * 1024 / 4);
    transpose_k<<<dim3(32, 32),  256, 0, stream>>>(Wq, wqkvT,                1024, 1024);
    transpose_k<<<dim3(32, 32),  256, 0, stream>>>(Wk, wqkvT + 1024 * 1024,  1024, 1024);
    transpose_k<<<dim3(32, 32),  256, 0, stream>>>(Wv, wqkvT + 2048 * 1024,  1024, 1024);
    transpose_k<<<dim3(32, 32),  256, 0, stream>>>(Wo, woT,                  1024, 1024);
    transpose_k<<<dim3(128, 32), 256, 0, stream>>>(W1, w1T, 1024, 4096);
    transpose_k<<<dim3(32, 128), 256, 0, stream>>>(W2, w2T, 4096, 1024);
    concat3_k<<<12, 256, 0, stream>>>(bq, bk, bv, bqkv);

    // QKV projection: 8-phase 256^2 (192 blocks)
    gemm256_bt<0><<<dim3(12, 16), 512, 0, stream>>>(xb, wqkvT, bqkv, qkv, M, 3072, 1024);
    // per-head V^T
    vtrans_k<<<dim3(64, 2, 32), 256, 0, stream>>>(qkv, vtb);
    // attention -> ctx bf16
    attn_k<<<dim3(32, 32), 256, 0, stream>>>(qkv, vtb, pm, ctxb);
    // attn_out + residual: r1 = ctx@Wo + bo + x  (f32)
    gemm_bt<2><<<dim3(8, 32), 256, 0, stream>>>(ctxb, woT, bo, x, r1f, M, 1024, 1024);
    // LN1 -> x1 (f32 + bf16)
    ln_k<1><<<4096, 256, 0, stream>>>(r1f, g1, be1, x1f, x1b);
    // FF1: relu(x1@W1 + b1) -> hb bf16 : 8-phase 256^2 (256 blocks)
    gemm256_bt<1><<<dim3(16, 16), 512, 0, stream>>>(x1b, w1T, b1, hb, M, 4096, 1024);
    // FF2 + residual: r1 = hb@W2 + b2 + x1  (f32)
    gemm_bt<2><<<dim3(8, 32), 256, 0, stream>>>(hb, w2T, b2, x1f, r1f, M, 1024, 4096);
    // LN2 -> out
    ln_k<0><<<4096, 256, 0, stream>>>(r1f, g2, be2, (float*)d_out, nullptr);
}